// Round 2
// baseline (3791.255 us; speedup 1.0000x reference)
//
#include <hip/hip_runtime.h>
#include <hip/hip_bf16.h>

#define TT 16
#define CC 320
#define HH 8
#define DD 40

__device__ __forceinline__ float bfu2f(unsigned short u) {
    union { unsigned int u; float f; } c; c.u = ((unsigned int)u) << 16; return c.f;
}
__device__ __forceinline__ unsigned short f2bfu(float f) {
    union { float f; unsigned int u; } c; c.f = f;
    unsigned int x = c.u;
    return (unsigned short)((x + 0x7fffu + ((x >> 16) & 1u)) >> 16);
}
__device__ __forceinline__ void unpk2(unsigned int u, float& lo, float& hi) {
    union { unsigned int u; float f; } a, b;
    a.u = u << 16; b.u = u & 0xffff0000u;
    lo = a.f; hi = b.f;
}

__global__ __launch_bounds__(320)
void ta_fused(const float* __restrict__ x,
              const float* __restrict__ Wq,
              const float* __restrict__ Wk,
              const float* __restrict__ Wv,
              const float* __restrict__ Wo,
              const float* __restrict__ bo,
              const float* __restrict__ relk,
              const float* __restrict__ relv,
              float* __restrict__ out)
{
    __shared__ alignas(16) unsigned short xtT[CC * TT]; // bf16 x, [ch][t]
    __shared__ alignas(16) float qs[TT * CC];           // q*scale [t][c]; reused as attn[h][t][s]
    __shared__ alignas(16) float ks[TT * CC];           // k [t][c]; reused as aoT [c][t]
    __shared__ alignas(16) unsigned short vsb[TT * CC]; // bf16 v [t][c]

    const int tid = threadIdx.x;
    const int n   = blockIdx.x;
    const int bi  = n >> 10;
    const int sp  = n & 1023;

    const float* xb = x + (size_t)bi * (TT * CC * 1024) + sp;

    {   // Phase 0: gather x tile
        const int ch = tid;
        #pragma unroll
        for (int t = 0; t < TT; ++t) {
            float v = xb[(size_t)(t * CC + ch) * 1024];
            xtT[ch * TT + t] = f2bfu(v);
        }
    }
    __syncthreads();

    {   // Phase 1: QKV
        const int i = tid;
        const float* wq = Wq + i * CC;
        const float* wk = Wk + i * CC;
        const float* wv = Wv + i * CC;
        float aq[TT], ak[TT], av[TT];
        #pragma unroll
        for (int t = 0; t < TT; ++t) { aq[t] = 0.f; ak[t] = 0.f; av[t] = 0.f; }
        #pragma unroll 2
        for (int ch = 0; ch < CC; ++ch) {
            float qw = wq[ch], kw = wk[ch], vw = wv[ch];
            const uint4* xp = reinterpret_cast<const uint4*>(xtT + ch * TT);
            uint4 p0 = xp[0];
            uint4 p1 = xp[1];
            float xv[TT];
            unpk2(p0.x, xv[0],  xv[1]);  unpk2(p0.y, xv[2],  xv[3]);
            unpk2(p0.z, xv[4],  xv[5]);  unpk2(p0.w, xv[6],  xv[7]);
            unpk2(p1.x, xv[8],  xv[9]);  unpk2(p1.y, xv[10], xv[11]);
            unpk2(p1.z, xv[12], xv[13]); unpk2(p1.w, xv[14], xv[15]);
            #pragma unroll
            for (int t = 0; t < TT; ++t) {
                aq[t] = fmaf(xv[t], qw, aq[t]);
                ak[t] = fmaf(xv[t], kw, ak[t]);
                av[t] = fmaf(xv[t], vw, av[t]);
            }
        }
        const float scale = 0.15811388300841897f;
        #pragma unroll
        for (int t = 0; t < TT; ++t) {
            qs[t * CC + i]  = aq[t] * scale;
            ks[t * CC + i]  = ak[t];
            vsb[t * CC + i] = f2bfu(av[t]);
        }
    }
    __syncthreads();

    // Phase 2a: scores + masked softmax (threads 0..127, one per (h,t))
    float arow[TT];
    int hh = 0, tt = 0;
    if (tid < HH * TT) {
        hh = tid >> 4; tt = tid & 15;
        const float* qrow = qs + tt * CC + hh * DD;
        float qr[DD];
        #pragma unroll
        for (int d2 = 0; d2 < DD; ++d2) qr[d2] = qrow[d2];
        float m = -1e30f;
        #pragma unroll
        for (int s = 0; s < TT; ++s) {
            const float* krow = ks + s * CC + hh * DD;
            const float* rk   = relk + (s - tt + TT) * DD;
            float acc = 0.f, acc2 = 0.f;
            #pragma unroll
            for (int d2 = 0; d2 < DD; ++d2) {
                acc  = fmaf(qr[d2], krow[d2], acc);
                acc2 = fmaf(qr[d2], rk[d2],  acc2);
            }
            float sv = acc + acc2;
            arow[s] = (s <= tt) ? sv : -1e30f;
            m = fmaxf(m, arow[s]);
        }
        float sum = 0.f;
        #pragma unroll
        for (int s = 0; s < TT; ++s) {
            arow[s] = __expf(arow[s] - m);
            sum += arow[s];
        }
        float inv = 1.f / sum;
        #pragma unroll
        for (int s = 0; s < TT; ++s) arow[s] *= inv;
    }
    __syncthreads();
    if (tid < HH * TT) {
        float* adst = qs + (hh * TT + tt) * TT;
        #pragma unroll
        for (int s = 0; s < TT; ++s) adst[s] = arow[s];
    }
    __syncthreads();

    {   // Phase 2b: attn @ (v + rel_v)
        const int i  = tid;
        const int h  = i / DD;
        const int d2 = i % DD;
        float rv[TT];
        #pragma unroll
        for (int j = 0; j < TT; ++j) rv[j] = relv[(j + 1) * DD + d2];
        float* aoT = ks;
        #pragma unroll
        for (int t = 0; t < TT; ++t) {
            const float* ar = qs + (h * TT + t) * TT;
            float acc = 0.f;
            #pragma unroll
            for (int s = 0; s < TT; ++s) {
                if (s <= t) {
                    float vv = bfu2f(vsb[s * CC + i]);
                    acc = fmaf(ar[s], vv + rv[s - t + 15], acc);
                }
            }
            aoT[i * TT + t] = acc;
        }
    }
    __syncthreads();

    {   // Phase 3: out projection + bias + residual, scatter
        const int i = tid;
        const float* wo  = Wo + i * CC;
        const float* aoT = ks;
        float acc[TT];
        #pragma unroll
        for (int t = 0; t < TT; ++t) acc[t] = 0.f;
        #pragma unroll 2
        for (int ch = 0; ch < CC; ++ch) {
            float w = wo[ch];
            const float4* ap = reinterpret_cast<const float4*>(aoT + ch * TT);
            float4 a0 = ap[0], a1 = ap[1], a2 = ap[2], a3 = ap[3];
            acc[0]  = fmaf(a0.x, w, acc[0]);   acc[1]  = fmaf(a0.y, w, acc[1]);
            acc[2]  = fmaf(a0.z, w, acc[2]);   acc[3]  = fmaf(a0.w, w, acc[3]);
            acc[4]  = fmaf(a1.x, w, acc[4]);   acc[5]  = fmaf(a1.y, w, acc[5]);
            acc[6]  = fmaf(a1.z, w, acc[6]);   acc[7]  = fmaf(a1.w, w, acc[7]);
            acc[8]  = fmaf(a2.x, w, acc[8]);   acc[9]  = fmaf(a2.y, w, acc[9]);
            acc[10] = fmaf(a2.z, w, acc[10]);  acc[11] = fmaf(a2.w, w, acc[11]);
            acc[12] = fmaf(a3.x, w, acc[12]);  acc[13] = fmaf(a3.y, w, acc[13]);
            acc[14] = fmaf(a3.z, w, acc[14]);  acc[15] = fmaf(a3.w, w, acc[15]);
        }
        const float bv = bo[i];
        float* ob = out + (size_t)bi * (TT * CC * 1024) + sp;
        #pragma unroll
        for (int t = 0; t < TT; ++t) {
            float res = bfu2f(xtT[i * TT + t]);
            ob[(size_t)(t * CC + i) * 1024] = acc[t] + bv + res;
        }
    }
}

extern "C" void kernel_launch(void* const* d_in, const int* in_sizes, int n_in,
                              void* d_out, int out_size, void* d_ws, size_t ws_size,
                              hipStream_t stream) {
    const float* x   = (const float*)d_in[0];
    const float* Wq  = (const float*)d_in[1];
    const float* Wk  = (const float*)d_in[2];
    const float* Wv  = (const float*)d_in[3];
    const float* Wo  = (const float*)d_in[4];
    const float* bo  = (const float*)d_in[5];
    const float* rk  = (const float*)d_in[6];
    const float* rv  = (const float*)d_in[7];
    float* out = (float*)d_out;

    const int b = in_sizes[0] / (TT * CC * 1024);
    dim3 grid(b * 1024), block(320);
    hipLaunchKernelGGL(ta_fused, grid, block, 0, stream,
                       x, Wq, Wk, Wv, Wo, bo, rk, rv, out);
}

// Round 3
// 611.254 us; speedup vs baseline: 6.2024x; 6.2024x over previous
//
#include <hip/hip_runtime.h>
#include <hip/hip_bf16.h>

#define TT 16
#define CC 320
#define HH 8
#define DD 40
#define NSLOT 328        // padded LDS row (bf16): 656B = 164 dw, %32=4 -> 2-way max

using bf16x8 = __attribute__((ext_vector_type(8))) short;
using f32x4  = __attribute__((ext_vector_type(4))) float;

__device__ __forceinline__ float bfu2f(unsigned short u) {
    union { unsigned int u; float f; } c; c.u = ((unsigned int)u) << 16; return c.f;
}
__device__ __forceinline__ unsigned short f2bfu(float f) {
    union { float f; unsigned int u; } c; c.f = f;
    unsigned int x = c.u;
    return (unsigned short)((x + 0x7fffu + ((x >> 16) & 1u)) >> 16);
}
__device__ __forceinline__ void unpk2(unsigned int u, float& lo, float& hi) {
    union { unsigned int u; float f; } a, b;
    a.u = u << 16; b.u = u & 0xffff0000u;
    lo = a.f; hi = b.f;
}
__device__ __forceinline__ void unpk8(const unsigned short* p, float* o) {
    uint4 u = *reinterpret_cast<const uint4*>(p);
    unpk2(u.x, o[0], o[1]); unpk2(u.y, o[2], o[3]);
    unpk2(u.z, o[4], o[5]); unpk2(u.w, o[6], o[7]);
}

// ---- K0: weight prep (fp32 -> bf16; q-scale folded into Wq) ----
__global__ __launch_bounds__(256)
void prep_weights(const float* __restrict__ Wq, const float* __restrict__ Wk,
                  const float* __restrict__ Wv, const float* __restrict__ Wo,
                  unsigned short* __restrict__ wqkv, unsigned short* __restrict__ wo)
{
    int i = blockIdx.x * 256 + threadIdx.x;
    if (i < 960 * 320) {
        int n = i / 320, k = i % 320;
        float v;
        if (n < 320)      v = Wq[n * 320 + k] * 0.15811388300841897f; // d^-0.5 folded
        else if (n < 640) v = Wk[(n - 320) * 320 + k];
        else              v = Wv[(n - 640) * 320 + k];
        wqkv[i] = f2bfu(v);
    }
    int j = i - 960 * 320;
    if (j >= 0 && j < 320 * 320) wo[j] = f2bfu(Wo[j]);
}

// ---- main fused kernel: 2 sequences per block, 4 waves ----
// LDS map (ushort units), per-seq stride S1=15744 (q:0, k:+5248, v:+10496):
//   xr overlay   [2][16][NSLOT] @0        (= q0+k0; dead after A-frag load)
//   attn overlay f32[2][8][16][16] @0     (16KB; over dead q0 + part of k0)
//   ao overlay   [2][16][NSLOT] @15744    (over dead q1+k1)
//   relk' rows1..16 [16][40] @31488
__global__ __launch_bounds__(256, 2)
void ta_mfma(const float* __restrict__ x,
             const unsigned short* __restrict__ wqkv,
             const unsigned short* __restrict__ wo,
             const float* __restrict__ bo,
             const float* __restrict__ relk,
             const float* __restrict__ relv,
             float* __restrict__ out)
{
    __shared__ unsigned short lds[2 * 3 * 16 * NSLOT + 16 * DD]; // 64256 B

    const int tid  = threadIdx.x;
    const int lane = tid & 63;
    const int wv   = tid >> 6;
    const int s0   = blockIdx.x * 2;       // two consecutive spatial positions
    const int bi   = s0 >> 10;
    const int sp   = s0 & 1023;            // even

    const float* xb = x + (size_t)bi * (TT * CC) * 1024 + sp;

    // ---- Phase 0: gather x (float2 over the 2 seqs) -> xr bf16; stage relk' ----
    for (int p = tid; p < TT * CC; p += 256) {
        float2 xv = *reinterpret_cast<const float2*>(xb + (size_t)p * 1024);
        int t = p / CC, ch = p - (p / CC) * CC;
        lds[0 * 5248 + t * NSLOT + ch] = f2bfu(xv.x);
        lds[1 * 5248 + t * NSLOT + ch] = f2bfu(xv.y);
    }
    for (int p = tid; p < 16 * DD; p += 256)
        lds[31488 + p] = f2bfu(relk[DD + p]);         // rows 1..16
    __syncthreads();

    // ---- Phase 1: A1 fragments (xr) -> registers ----
    bf16x8 afr[2][10];
    {
        int t = lane & 15, g = lane >> 4;
        #pragma unroll
        for (int m = 0; m < 2; ++m)
            #pragma unroll
            for (int k0 = 0; k0 < 10; ++k0)
                afr[m][k0] = *reinterpret_cast<const bf16x8*>(
                    &lds[m * 5248 + t * NSLOT + k0 * 32 + g * 8]);
    }
    __syncthreads();   // xr may now be overwritten

    // ---- Phase 2: QKV GEMM (MFMA), 15 N-tiles per wave, B streamed from L2 ----
    {
        int t16 = lane & 15, g = lane >> 4;
        for (int i = 0; i < 15; ++i) {
            int T  = wv * 15 + i;
            int n0 = T * 16;
            f32x4 c0 = {0.f, 0.f, 0.f, 0.f}, c1 = {0.f, 0.f, 0.f, 0.f};
            const unsigned short* bp = wqkv + (n0 + t16) * 320 + g * 8;
            #pragma unroll
            for (int k0 = 0; k0 < 10; ++k0) {
                bf16x8 b = *reinterpret_cast<const bf16x8*>(bp + k0 * 32);
                c0 = __builtin_amdgcn_mfma_f32_16x16x32_bf16(afr[0][k0], b, c0, 0, 0, 0);
                c1 = __builtin_amdgcn_mfma_f32_16x16x32_bf16(afr[1][k0], b, c1, 0, 0, 0);
            }
            int which = T / 20;                        // 0=q,1=k,2=v (tiles aligned: 320%16==0)
            int cin   = (T - which * 20) * 16 + t16;
            #pragma unroll
            for (int r = 0; r < 4; ++r) {
                int t = g * 4 + r;
                lds[0 * 15744 + which * 5248 + t * NSLOT + cin] = f2bfu(c0[r]);
                lds[1 * 15744 + which * 5248 + t * NSLOT + cin] = f2bfu(c1[r]);
            }
        }
    }
    __syncthreads();

    // ---- Phase 2a: sim + masked softmax; thread = (seq, h, t) ----
    float arow[16];
    {
        int sq = tid >> 7, h = (tid >> 4) & 7, t = tid & 15;
        const unsigned short* qrow = &lds[sq * 15744 + t * NSLOT + h * DD];
        float qf[40];
        #pragma unroll
        for (int c5 = 0; c5 < 5; ++c5) unpk8(qrow + c5 * 8, qf + c5 * 8);
        float mx = -1e30f;
        #pragma unroll
        for (int s = 0; s < 16; ++s) {
            const unsigned short* krow = &lds[sq * 15744 + 5248 + s * NSLOT + h * DD];
            const unsigned short* rk   = &lds[31488 + ((s - t + 15) & 15) * DD];
            float acc = 0.f, acc2 = 0.f;
            #pragma unroll
            for (int c5 = 0; c5 < 5; ++c5) {
                float kf[8], rf[8];
                unpk8(krow + c5 * 8, kf);
                unpk8(rk   + c5 * 8, rf);
                #pragma unroll
                for (int j = 0; j < 8; ++j) {
                    acc  = fmaf(qf[c5 * 8 + j], kf[j], acc);   // q already scaled
                    acc2 = fmaf(qf[c5 * 8 + j], rf[j], acc2);
                }
            }
            float sv = acc + acc2;
            arow[s] = (s <= t) ? sv : -1e30f;
            mx = fmaxf(mx, arow[s]);
        }
        float sum = 0.f;
        #pragma unroll
        for (int s = 0; s < 16; ++s) { arow[s] = __expf(arow[s] - mx); sum += arow[s]; }
        float inv = 1.f / sum;
        #pragma unroll
        for (int s = 0; s < 16; ++s) arow[s] *= inv;
    }
    __syncthreads();   // all q/k reads done
    {
        int sq = tid >> 7, h = (tid >> 4) & 7, t = tid & 15;
        float* attn = reinterpret_cast<float*>(lds);
        #pragma unroll
        for (int s = 0; s < 16; ++s) attn[sq * 2048 + h * 256 + t * 16 + s] = arow[s];
    }
    __syncthreads();

    // ---- Phase 2b: ao = attn @ (v + rel_v); thread = (seq, c) ----
    {
        const float* attnf = reinterpret_cast<const float*>(lds);
        for (int base = 0; base < 2 * CC; base += 256) {
            int p = base + tid;
            if (p < 2 * CC) {
                int sq = p / CC, c = p - sq * CC;
                int h = c / DD, d = c - h * DD;
                const unsigned short* vcol = &lds[sq * 15744 + 10496 + c];
                float acc[16];
                #pragma unroll
                for (int t = 0; t < 16; ++t) acc[t] = 0.f;
                #pragma unroll
                for (int s = 0; s < 16; ++s) {
                    float vvv = bfu2f(vcol[s * NSLOT]);
                    #pragma unroll
                    for (int t = s; t < 16; ++t) {
                        float a   = attnf[sq * 2048 + h * 256 + t * 16 + s];
                        float rvv = relv[(s - t + 16) * DD + d];
                        acc[t] = fmaf(a, vvv + rvv, acc[t]);
                    }
                }
                #pragma unroll
                for (int t = 0; t < 16; ++t)
                    lds[15744 + sq * 5248 + t * NSLOT + c] = f2bfu(acc[t]);
            }
        }
    }
    __syncthreads();

    // ---- Phase 3: out = ao @ Wo^T + bo + x, scatter (float2 over 2 seqs) ----
    {
        int t16 = lane & 15, g = lane >> 4;
        bf16x8 afr2[2][10];
        #pragma unroll
        for (int m = 0; m < 2; ++m)
            #pragma unroll
            for (int k0 = 0; k0 < 10; ++k0)
                afr2[m][k0] = *reinterpret_cast<const bf16x8*>(
                    &lds[15744 + m * 5248 + t16 * NSLOT + k0 * 32 + g * 8]);

        float* ob = out + (size_t)bi * (TT * CC) * 1024 + sp;
        for (int i = 0; i < 5; ++i) {
            int n0 = (wv * 5 + i) * 16;
            f32x4 c0 = {0.f, 0.f, 0.f, 0.f}, c1 = {0.f, 0.f, 0.f, 0.f};
            const unsigned short* bp = wo + (n0 + t16) * 320 + g * 8;
            #pragma unroll
            for (int k0 = 0; k0 < 10; ++k0) {
                bf16x8 b = *reinterpret_cast<const bf16x8*>(bp + k0 * 32);
                c0 = __builtin_amdgcn_mfma_f32_16x16x32_bf16(afr2[0][k0], b, c0, 0, 0, 0);
                c1 = __builtin_amdgcn_mfma_f32_16x16x32_bf16(afr2[1][k0], b, c1, 0, 0, 0);
            }
            int ch = n0 + t16;
            float bias = bo[ch];
            #pragma unroll
            for (int r = 0; r < 4; ++r) {
                int t = g * 4 + r;
                size_t off = (size_t)(t * CC + ch) * 1024;
                float2 res = *reinterpret_cast<const float2*>(xb + off);  // fp32 residual
                float2 o2;
                o2.x = c0[r] + bias + res.x;
                o2.y = c1[r] + bias + res.y;
                *reinterpret_cast<float2*>(ob + off) = o2;
            }
        }
    }
}

extern "C" void kernel_launch(void* const* d_in, const int* in_sizes, int n_in,
                              void* d_out, int out_size, void* d_ws, size_t ws_size,
                              hipStream_t stream) {
    const float* x   = (const float*)d_in[0];
    const float* Wq  = (const float*)d_in[1];
    const float* Wk  = (const float*)d_in[2];
    const float* Wv  = (const float*)d_in[3];
    const float* Wo  = (const float*)d_in[4];
    const float* bo  = (const float*)d_in[5];
    const float* rk  = (const float*)d_in[6];
    const float* rv  = (const float*)d_in[7];
    float* out = (float*)d_out;

    unsigned short* wqkv = (unsigned short*)d_ws;          // 960*320 bf16
    unsigned short* wob  = wqkv + 960 * 320;               // 320*320 bf16

    hipLaunchKernelGGL(prep_weights, dim3(1600), dim3(256), 0, stream,
                       Wq, Wk, Wv, Wo, wqkv, wob);

    const int b = in_sizes[0] / (TT * CC * 1024);
    const int nseq = b * 1024;
    hipLaunchKernelGGL(ta_mfma, dim3(nseq / 2), dim3(256), 0, stream,
                       x, wqkv, wob, bo, rk, rv, out);
}

// Round 4
// 438.390 us; speedup vs baseline: 8.6481x; 1.3943x over previous
//
#include <hip/hip_runtime.h>
#include <hip/hip_bf16.h>

#define TT 16
#define CC 320
#define HH 8
#define DD 40
#define NSLOT 328        // padded LDS row (bf16)

using bf16x8 = __attribute__((ext_vector_type(8))) short;
using f32x4  = __attribute__((ext_vector_type(4))) float;

__device__ __forceinline__ float bfu2f(unsigned short u) {
    union { unsigned int u; float f; } c; c.u = ((unsigned int)u) << 16; return c.f;
}
__device__ __forceinline__ unsigned short f2bfu(float f) {
    union { float f; unsigned int u; } c; c.f = f;
    unsigned int x = c.u;
    return (unsigned short)((x + 0x7fffu + ((x >> 16) & 1u)) >> 16);
}
__device__ __forceinline__ void unpk2(unsigned int u, float& lo, float& hi) {
    union { unsigned int u; float f; } a, b;
    a.u = u << 16; b.u = u & 0xffff0000u;
    lo = a.f; hi = b.f;
}
__device__ __forceinline__ void unpk8(const unsigned short* p, float* o) {
    uint4 u = *reinterpret_cast<const uint4*>(p);
    unpk2(u.x, o[0], o[1]); unpk2(u.y, o[2], o[3]);
    unpk2(u.z, o[4], o[5]); unpk2(u.w, o[6], o[7]);
}

// ---- K0: weight prep (fp32 -> bf16; q-scale folded into Wq) ----
__global__ __launch_bounds__(256)
void prep_weights(const float* __restrict__ Wq, const float* __restrict__ Wk,
                  const float* __restrict__ Wv, const float* __restrict__ Wo,
                  unsigned short* __restrict__ wqkv, unsigned short* __restrict__ wo)
{
    int i = blockIdx.x * 256 + threadIdx.x;
    if (i < 960 * 320) {
        int n = i / 320, k = i % 320;
        float v;
        if (n < 320)      v = Wq[n * 320 + k] * 0.15811388300841897f;
        else if (n < 640) v = Wk[(n - 320) * 320 + k];
        else              v = Wv[(n - 640) * 320 + k];
        wqkv[i] = f2bfu(v);
    }
    int j = i - 960 * 320;
    if (j >= 0 && j < 320 * 320) wo[j] = f2bfu(Wo[j]);
}

// ---- K1: x[b][tc=5120][sp=1024] f32 -> xr[b][sp=1024][tc=5120] bf16 ----
__global__ __launch_bounds__(256)
void transpose_in(const float* __restrict__ x, unsigned short* __restrict__ xr)
{
    __shared__ unsigned short tile[64][68];   // [sp_l][tc_l]
    const int gx  = blockIdx.x;
    const int spT = gx & 15;
    const int tcT = (gx >> 4) % 80;
    const int bi  = gx / (16 * 80);
    const int c4  = threadIdx.x & 15, rb = threadIdx.x >> 4;

    const float* xb = x + (size_t)bi * 5120 * 1024;
    #pragma unroll
    for (int rr = 0; rr < 4; ++rr) {
        int tc_l = rr * 16 + rb;
        float4 v = *reinterpret_cast<const float4*>(
            xb + (size_t)(tcT * 64 + tc_l) * 1024 + spT * 64 + c4 * 4);
        tile[c4 * 4 + 0][tc_l] = f2bfu(v.x);
        tile[c4 * 4 + 1][tc_l] = f2bfu(v.y);
        tile[c4 * 4 + 2][tc_l] = f2bfu(v.z);
        tile[c4 * 4 + 3][tc_l] = f2bfu(v.w);
    }
    __syncthreads();
    unsigned short* xo = xr + (size_t)bi * 1024 * 5120;
    #pragma unroll
    for (int rr = 0; rr < 4; ++rr) {
        int sp_l = rr * 16 + rb;
        ushort4 u = *reinterpret_cast<const ushort4*>(&tile[sp_l][c4 * 4]);
        *reinterpret_cast<ushort4*>(
            xo + (size_t)(spT * 64 + sp_l) * 5120 + tcT * 64 + c4 * 4) = u;
    }
}

// ---- K2: fused QKV + attention + out-proj; y[seq][t][c] f32 (coalesced) ----
__global__ __launch_bounds__(256, 2)
void ta_mfma2(const unsigned short* __restrict__ xr,
              const unsigned short* __restrict__ wqkv,
              const unsigned short* __restrict__ wo,
              const float* __restrict__ bo,
              const float* __restrict__ relk,
              const float* __restrict__ relv,
              float* __restrict__ y)
{
    __shared__ unsigned short lds[2 * 3 * 16 * NSLOT + 16 * DD]; // 64256 B

    const int tid  = threadIdx.x;
    const int lane = tid & 63;
    const int wv   = tid >> 6;
    const int s0   = blockIdx.x * 2;

    // stage relk rows 1..16 (barrier after phase 2 covers this)
    for (int p = tid; p < 16 * DD; p += 256)
        lds[31488 + p] = f2bfu(relk[DD + p]);

    // ---- A-fragments straight from global xr (contiguous per seq) ----
    bf16x8 afr[2][10];
    {
        int t16 = lane & 15, g = lane >> 4;
        const unsigned short* base = xr + (size_t)s0 * 5120 + t16 * 320 + g * 8;
        #pragma unroll
        for (int m = 0; m < 2; ++m)
            #pragma unroll
            for (int k0 = 0; k0 < 10; ++k0)
                afr[m][k0] = *reinterpret_cast<const bf16x8*>(base + m * 5120 + k0 * 32);
    }

    // ---- Phase 2: QKV GEMM (MFMA), B streamed from L2 ----
    {
        int t16 = lane & 15, g = lane >> 4;
        for (int i = 0; i < 15; ++i) {
            int T  = wv * 15 + i;
            int n0 = T * 16;
            f32x4 c0 = {0.f, 0.f, 0.f, 0.f}, c1 = {0.f, 0.f, 0.f, 0.f};
            const unsigned short* bp = wqkv + (n0 + t16) * 320 + g * 8;
            #pragma unroll
            for (int k0 = 0; k0 < 10; ++k0) {
                bf16x8 b = *reinterpret_cast<const bf16x8*>(bp + k0 * 32);
                c0 = __builtin_amdgcn_mfma_f32_16x16x32_bf16(afr[0][k0], b, c0, 0, 0, 0);
                c1 = __builtin_amdgcn_mfma_f32_16x16x32_bf16(afr[1][k0], b, c1, 0, 0, 0);
            }
            int which = T / 20;
            int cin   = (T - which * 20) * 16 + t16;
            #pragma unroll
            for (int r = 0; r < 4; ++r) {
                int t = g * 4 + r;
                lds[0 * 15744 + which * 5248 + t * NSLOT + cin] = f2bfu(c0[r]);
                lds[1 * 15744 + which * 5248 + t * NSLOT + cin] = f2bfu(c1[r]);
            }
        }
    }
    __syncthreads();

    // ---- Phase 2a: sim + masked softmax; thread = (seq, h, t) ----
    float arow[16];
    {
        int sq = tid >> 7, h = (tid >> 4) & 7, t = tid & 15;
        const unsigned short* qrow = &lds[sq * 15744 + t * NSLOT + h * DD];
        float qf[40];
        #pragma unroll
        for (int c5 = 0; c5 < 5; ++c5) unpk8(qrow + c5 * 8, qf + c5 * 8);
        float mx = -1e30f;
        #pragma unroll
        for (int s = 0; s < 16; ++s) {
            const unsigned short* krow = &lds[sq * 15744 + 5248 + s * NSLOT + h * DD];
            const unsigned short* rk   = &lds[31488 + ((s - t + 15) & 15) * DD];
            float acc = 0.f, acc2 = 0.f;
            #pragma unroll
            for (int c5 = 0; c5 < 5; ++c5) {
                float kf[8], rf[8];
                unpk8(krow + c5 * 8, kf);
                unpk8(rk   + c5 * 8, rf);
                #pragma unroll
                for (int j = 0; j < 8; ++j) {
                    acc  = fmaf(qf[c5 * 8 + j], kf[j], acc);
                    acc2 = fmaf(qf[c5 * 8 + j], rf[j], acc2);
                }
            }
            float sv = acc + acc2;
            arow[s] = (s <= t) ? sv : -1e30f;
            mx = fmaxf(mx, arow[s]);
        }
        float sum = 0.f;
        #pragma unroll
        for (int s = 0; s < 16; ++s) { arow[s] = __expf(arow[s] - mx); sum += arow[s]; }
        float inv = 1.f / sum;
        #pragma unroll
        for (int s = 0; s < 16; ++s) arow[s] *= inv;
    }
    __syncthreads();
    {
        int sq = tid >> 7, h = (tid >> 4) & 7, t = tid & 15;
        float* attn = reinterpret_cast<float*>(lds);
        #pragma unroll
        for (int s = 0; s < 16; ++s) attn[sq * 2048 + h * 256 + t * 16 + s] = arow[s];
    }
    __syncthreads();

    // ---- Phase 2b: ao = attn @ (v + rel_v) ----
    {
        const float* attnf = reinterpret_cast<const float*>(lds);
        for (int base = 0; base < 2 * CC; base += 256) {
            int p = base + tid;
            if (p < 2 * CC) {
                int sq = p / CC, c = p - sq * CC;
                int h = c / DD, d = c - h * DD;
                const unsigned short* vcol = &lds[sq * 15744 + 10496 + c];
                float acc[16];
                #pragma unroll
                for (int t = 0; t < 16; ++t) acc[t] = 0.f;
                #pragma unroll
                for (int s = 0; s < 16; ++s) {
                    float vvv = bfu2f(vcol[s * NSLOT]);
                    #pragma unroll
                    for (int t = s; t < 16; ++t) {
                        float a   = attnf[sq * 2048 + h * 256 + t * 16 + s];
                        float rvv = relv[(s - t + 16) * DD + d];
                        acc[t] = fmaf(a, vvv + rvv, acc[t]);
                    }
                }
                #pragma unroll
                for (int t = 0; t < 16; ++t)
                    lds[15744 + sq * 5248 + t * NSLOT + c] = f2bfu(acc[t]);
            }
        }
    }
    __syncthreads();

    // ---- Phase 3: y = ao @ Wo^T + bo (coalesced seq-major store) ----
    {
        int t16 = lane & 15, g = lane >> 4;
        bf16x8 afr2[2][10];
        #pragma unroll
        for (int m = 0; m < 2; ++m)
            #pragma unroll
            for (int k0 = 0; k0 < 10; ++k0)
                afr2[m][k0] = *reinterpret_cast<const bf16x8*>(
                    &lds[15744 + m * 5248 + t16 * NSLOT + k0 * 32 + g * 8]);

        for (int i = 0; i < 5; ++i) {
            int n0 = (wv * 5 + i) * 16;
            f32x4 c0 = {0.f, 0.f, 0.f, 0.f}, c1 = {0.f, 0.f, 0.f, 0.f};
            const unsigned short* bp = wo + (n0 + t16) * 320 + g * 8;
            #pragma unroll
            for (int k0 = 0; k0 < 10; ++k0) {
                bf16x8 b = *reinterpret_cast<const bf16x8*>(bp + k0 * 32);
                c0 = __builtin_amdgcn_mfma_f32_16x16x32_bf16(afr2[0][k0], b, c0, 0, 0, 0);
                c1 = __builtin_amdgcn_mfma_f32_16x16x32_bf16(afr2[1][k0], b, c1, 0, 0, 0);
            }
            int ch = n0 + t16;
            float bias = bo[ch];
            #pragma unroll
            for (int r = 0; r < 4; ++r) {
                int t = g * 4 + r;
                y[(size_t)s0 * 5120 + t * 320 + ch]       = c0[r] + bias;
                y[(size_t)(s0 + 1) * 5120 + t * 320 + ch] = c1[r] + bias;
            }
        }
    }
}

// ---- K3: out[b][tc][sp] = y[b][sp][tc] + x[b][tc][sp] ----
__global__ __launch_bounds__(256)
void transpose_out(const float* __restrict__ y, const float* __restrict__ x,
                   float* __restrict__ out)
{
    __shared__ float tile[64][68];   // [tc_l][sp_l]
    const int gx  = blockIdx.x;
    const int spT = gx & 15;
    const int tcT = (gx >> 4) % 80;
    const int bi  = gx / (16 * 80);
    const int c4  = threadIdx.x & 15, rb = threadIdx.x >> 4;

    const float* yb = y + (size_t)bi * 1024 * 5120;
    #pragma unroll
    for (int rr = 0; rr < 4; ++rr) {
        int sp_l = rr * 16 + rb;
        float4 v = *reinterpret_cast<const float4*>(
            yb + (size_t)(spT * 64 + sp_l) * 5120 + tcT * 64 + c4 * 4);
        tile[c4 * 4 + 0][sp_l] = v.x;
        tile[c4 * 4 + 1][sp_l] = v.y;
        tile[c4 * 4 + 2][sp_l] = v.z;
        tile[c4 * 4 + 3][sp_l] = v.w;
    }
    __syncthreads();
    const size_t base = (size_t)bi * 5120 * 1024;
    #pragma unroll
    for (int rr = 0; rr < 4; ++rr) {
        int tc_l = rr * 16 + rb;
        float4 t = *reinterpret_cast<const float4*>(&tile[tc_l][c4 * 4]);
        size_t off = base + (size_t)(tcT * 64 + tc_l) * 1024 + spT * 64 + c4 * 4;
        float4 xv = *reinterpret_cast<const float4*>(x + off);
        float4 o;
        o.x = t.x + xv.x; o.y = t.y + xv.y; o.z = t.z + xv.z; o.w = t.w + xv.w;
        *reinterpret_cast<float4*>(out + off) = o;
    }
}

// ---- fallback (round-3 proven kernel) for small ws_size ----
__global__ __launch_bounds__(256, 2)
void ta_mfma(const float* __restrict__ x,
             const unsigned short* __restrict__ wqkv,
             const unsigned short* __restrict__ wo,
             const float* __restrict__ bo,
             const float* __restrict__ relk,
             const float* __restrict__ relv,
             float* __restrict__ out)
{
    __shared__ unsigned short lds[2 * 3 * 16 * NSLOT + 16 * DD];

    const int tid  = threadIdx.x;
    const int lane = tid & 63;
    const int wv   = tid >> 6;
    const int s0   = blockIdx.x * 2;
    const int bi   = s0 >> 10;
    const int sp   = s0 & 1023;

    const float* xb = x + (size_t)bi * (TT * CC) * 1024 + sp;

    for (int p = tid; p < TT * CC; p += 256) {
        float2 xv = *reinterpret_cast<const float2*>(xb + (size_t)p * 1024);
        int t = p / CC, ch = p - (p / CC) * CC;
        lds[0 * 5248 + t * NSLOT + ch] = f2bfu(xv.x);
        lds[1 * 5248 + t * NSLOT + ch] = f2bfu(xv.y);
    }
    for (int p = tid; p < 16 * DD; p += 256)
        lds[31488 + p] = f2bfu(relk[DD + p]);
    __syncthreads();

    bf16x8 afr[2][10];
    {
        int t = lane & 15, g = lane >> 4;
        #pragma unroll
        for (int m = 0; m < 2; ++m)
            #pragma unroll
            for (int k0 = 0; k0 < 10; ++k0)
                afr[m][k0] = *reinterpret_cast<const bf16x8*>(
                    &lds[m * 5248 + t * NSLOT + k0 * 32 + g * 8]);
    }
    __syncthreads();

    {
        int t16 = lane & 15, g = lane >> 4;
        for (int i = 0; i < 15; ++i) {
            int T  = wv * 15 + i;
            int n0 = T * 16;
            f32x4 c0 = {0.f, 0.f, 0.f, 0.f}, c1 = {0.f, 0.f, 0.f, 0.f};
            const unsigned short* bp = wqkv + (n0 + t16) * 320 + g * 8;
            #pragma unroll
            for (int k0 = 0; k0 < 10; ++k0) {
                bf16x8 b = *reinterpret_cast<const bf16x8*>(bp + k0 * 32);
                c0 = __builtin_amdgcn_mfma_f32_16x16x32_bf16(afr[0][k0], b, c0, 0, 0, 0);
                c1 = __builtin_amdgcn_mfma_f32_16x16x32_bf16(afr[1][k0], b, c1, 0, 0, 0);
            }
            int which = T / 20;
            int cin   = (T - which * 20) * 16 + t16;
            #pragma unroll
            for (int r = 0; r < 4; ++r) {
                int t = g * 4 + r;
                lds[0 * 15744 + which * 5248 + t * NSLOT + cin] = f2bfu(c0[r]);
                lds[1 * 15744 + which * 5248 + t * NSLOT + cin] = f2bfu(c1[r]);
            }
        }
    }
    __syncthreads();

    float arow[16];
    {
        int sq = tid >> 7, h = (tid >> 4) & 7, t = tid & 15;
        const unsigned short* qrow = &lds[sq * 15744 + t * NSLOT + h * DD];
        float qf[40];
        #pragma unroll
        for (int c5 = 0; c5 < 5; ++c5) unpk8(qrow + c5 * 8, qf + c5 * 8);
        float mx = -1e30f;
        #pragma unroll
        for (int s = 0; s < 16; ++s) {
            const unsigned short* krow = &lds[sq * 15744 + 5248 + s * NSLOT + h * DD];
            const unsigned short* rk   = &lds[31488 + ((s - t + 15) & 15) * DD];
            float acc = 0.f, acc2 = 0.f;
            #pragma unroll
            for (int c5 = 0; c5 < 5; ++c5) {
                float kf[8], rf[8];
                unpk8(krow + c5 * 8, kf);
                unpk8(rk   + c5 * 8, rf);
                #pragma unroll
                for (int j = 0; j < 8; ++j) {
                    acc  = fmaf(qf[c5 * 8 + j], kf[j], acc);
                    acc2 = fmaf(qf[c5 * 8 + j], rf[j], acc2);
                }
            }
            float sv = acc + acc2;
            arow[s] = (s <= t) ? sv : -1e30f;
            mx = fmaxf(mx, arow[s]);
        }
        float sum = 0.f;
        #pragma unroll
        for (int s = 0; s < 16; ++s) { arow[s] = __expf(arow[s] - mx); sum += arow[s]; }
        float inv = 1.f / sum;
        #pragma unroll
        for (int s = 0; s < 16; ++s) arow[s] *= inv;
    }
    __syncthreads();
    {
        int sq = tid >> 7, h = (tid >> 4) & 7, t = tid & 15;
        float* attn = reinterpret_cast<float*>(lds);
        #pragma unroll
        for (int s = 0; s < 16; ++s) attn[sq * 2048 + h * 256 + t * 16 + s] = arow[s];
    }
    __syncthreads();

    {
        const float* attnf = reinterpret_cast<const float*>(lds);
        for (int base = 0; base < 2 * CC; base += 256) {
            int p = base + tid;
            if (p < 2 * CC) {
                int sq = p / CC, c = p - sq * CC;
                int h = c / DD, d = c - h * DD;
                const unsigned short* vcol = &lds[sq * 15744 + 10496 + c];
                float acc[16];
                #pragma unroll
                for (int t = 0; t < 16; ++t) acc[t] = 0.f;
                #pragma unroll
                for (int s = 0; s < 16; ++s) {
                    float vvv = bfu2f(vcol[s * NSLOT]);
                    #pragma unroll
                    for (int t = s; t < 16; ++t) {
                        float a   = attnf[sq * 2048 + h * 256 + t * 16 + s];
                        float rvv = relv[(s - t + 16) * DD + d];
                        acc[t] = fmaf(a, vvv + rvv, acc[t]);
                    }
                }
                #pragma unroll
                for (int t = 0; t < 16; ++t)
                    lds[15744 + sq * 5248 + t * NSLOT + c] = f2bfu(acc[t]);
            }
        }
    }
    __syncthreads();

    {
        int t16 = lane & 15, g = lane >> 4;
        bf16x8 afr2[2][10];
        #pragma unroll
        for (int m = 0; m < 2; ++m)
            #pragma unroll
            for (int k0 = 0; k0 < 10; ++k0)
                afr2[m][k0] = *reinterpret_cast<const bf16x8*>(
                    &lds[15744 + m * 5248 + t16 * NSLOT + k0 * 32 + g * 8]);

        float* ob = out + (size_t)bi * (TT * CC) * 1024 + sp;
        for (int i = 0; i < 5; ++i) {
            int n0 = (wv * 5 + i) * 16;
            f32x4 c0 = {0.f, 0.f, 0.f, 0.f}, c1 = {0.f, 0.f, 0.f, 0.f};
            const unsigned short* bp = wo + (n0 + t16) * 320 + g * 8;
            #pragma unroll
            for (int k0 = 0; k0 < 10; ++k0) {
                bf16x8 b = *reinterpret_cast<const bf16x8*>(bp + k0 * 32);
                c0 = __builtin_amdgcn_mfma_f32_16x16x32_bf16(afr2[0][k0], b, c0, 0, 0, 0);
                c1 = __builtin_amdgcn_mfma_f32_16x16x32_bf16(afr2[1][k0], b, c1, 0, 0, 0);
            }
            int ch = n0 + t16;
            float bias = bo[ch];
            #pragma unroll
            for (int r = 0; r < 4; ++r) {
                int t = g * 4 + r;
                size_t off = (size_t)(t * CC + ch) * 1024;
                float2 res = *reinterpret_cast<const float2*>(xb + off);
                float2 o2;
                o2.x = c0[r] + bias + res.x;
                o2.y = c1[r] + bias + res.y;
                *reinterpret_cast<float2*>(ob + off) = o2;
            }
        }
    }
}

extern "C" void kernel_launch(void* const* d_in, const int* in_sizes, int n_in,
                              void* d_out, int out_size, void* d_ws, size_t ws_size,
                              hipStream_t stream) {
    const float* x   = (const float*)d_in[0];
    const float* Wq  = (const float*)d_in[1];
    const float* Wk  = (const float*)d_in[2];
    const float* Wv  = (const float*)d_in[3];
    const float* Wo  = (const float*)d_in[4];
    const float* bo  = (const float*)d_in[5];
    const float* rk  = (const float*)d_in[6];
    const float* rv  = (const float*)d_in[7];
    float* out = (float*)d_out;

    unsigned short* wqkv = (unsigned short*)d_ws;          // 960*320 bf16
    unsigned short* wob  = wqkv + 960 * 320;               // 320*320 bf16

    const int b    = in_sizes[0] / (TT * CC * 1024);
    const int nseq = b * 1024;

    hipLaunchKernelGGL(prep_weights, dim3(1600), dim3(256), 0, stream,
                       Wq, Wk, Wv, Wo, wqkv, wob);

    const size_t xr_off = 819200;                          // weights, padded
    const size_t xr_sz  = (size_t)nseq * 5120 * 2;
    const size_t y_off  = xr_off + xr_sz;
    const size_t need   = y_off + (size_t)nseq * 5120 * 4;

    if (ws_size >= need) {
        unsigned short* xr = (unsigned short*)((char*)d_ws + xr_off);
        float*          yb = (float*)((char*)d_ws + y_off);
        hipLaunchKernelGGL(transpose_in, dim3(b * 1280), dim3(256), 0, stream, x, xr);
        hipLaunchKernelGGL(ta_mfma2, dim3(nseq / 2), dim3(256), 0, stream,
                           xr, wqkv, wob, bo, rk, rv, yb);
        hipLaunchKernelGGL(transpose_out, dim3(b * 1280), dim3(256), 0, stream,
                           yb, x, out);
    } else {
        hipLaunchKernelGGL(ta_mfma, dim3(nseq / 2), dim3(256), 0, stream,
                           x, wqkv, wob, bo, rk, rv, out);
    }
}